// Round 1
// baseline (1463.438 us; speedup 1.0000x reference)
//
#include <hip/hip_runtime.h>

#define B_N 32
#define C_N 512
#define T_N 4096
#define D_N 128
#define K_N 1024
#define N_N (B_N * T_N)   // 131072

// ---------------- workspace layout (bytes) ----------------
// ze      : [N_N * D_N] float      = 67,108,864
// enorm   : [K_N] float            @ 67,108,864
// ind     : [N_N] int              @ 67,112,960
// partials: [2048] float           @ 67,637,248
#define ZE_OFF   0
#define EN_OFF   67108864
#define IND_OFF  67112960
#define PART_OFF 67637248

// ---------------- codebook row norms ----------------
__global__ __launch_bounds__(64) void k_enorm(const float* __restrict__ E,
                                              float* __restrict__ en) {
  const int k = blockIdx.x;
  const int l = threadIdx.x;
  const float* e = E + (size_t)k * D_N;
  float a = e[l];
  float b = e[l + 64];
  float s = a * a + b * b;
  #pragma unroll
  for (int off = 32; off > 0; off >>= 1) s += __shfl_down(s, off);
  if (l == 0) en[k] = s;
}

// ---------------- projection GEMM: ze[b,t,d] = sum_c z[b,c,t]*W[d,c] + bias[d]
// grid (T/128, B), block 256.  128t x 128d tile, 8x8 per thread, BK=32.
__global__ __launch_bounds__(256) void k_proj(const float* __restrict__ z,
                                              const float* __restrict__ W,
                                              const float* __restrict__ bias,
                                              float* __restrict__ ze) {
  __shared__ __align__(16) float zs[32][128];   // [c][t]
  __shared__ __align__(16) float wsm[32][132];  // [c][d] (transposed W), padded

  const int b   = blockIdx.y;
  const int t0  = blockIdx.x * 128;
  const int tid = threadIdx.x;
  const int tx  = tid & 15;   // t sub-tile (8 t each)
  const int ty  = tid >> 4;   // d sub-tile (8 d each)

  float acc[8][8];
  #pragma unroll
  for (int i = 0; i < 8; ++i)
    #pragma unroll
    for (int j = 0; j < 8; ++j) acc[i][j] = 0.f;

  float bj[8];
  #pragma unroll
  for (int j = 0; j < 8; ++j) bj[j] = bias[ty * 8 + j];

  const float* zb = z + (size_t)b * C_N * T_N + t0;

  for (int c0 = 0; c0 < C_N; c0 += 32) {
    // stage z tile: 32 c-rows x 128 t, float4, coalesced along t
    #pragma unroll
    for (int u = tid; u < 1024; u += 256) {
      const int cc = u >> 5, t4 = u & 31;
      *(float4*)&zs[cc][t4 * 4] =
          *(const float4*)&zb[(size_t)(c0 + cc) * T_N + t4 * 4];
    }
    // stage W tile transposed: wsm[c][d] = W[d][c0+c]
    #pragma unroll
    for (int f = tid; f < 4096; f += 256) {
      const int d = f >> 5, cc = f & 31;
      wsm[cc][d] = W[d * C_N + c0 + cc];
    }
    __syncthreads();
    #pragma unroll
    for (int c = 0; c < 32; ++c) {
      const float4 a0 = *(const float4*)&zs[c][tx * 8];
      const float4 a1 = *(const float4*)&zs[c][tx * 8 + 4];
      const float4 w0 = *(const float4*)&wsm[c][ty * 8];
      const float4 w1 = *(const float4*)&wsm[c][ty * 8 + 4];
      const float av[8] = {a0.x, a0.y, a0.z, a0.w, a1.x, a1.y, a1.z, a1.w};
      const float wv[8] = {w0.x, w0.y, w0.z, w0.w, w1.x, w1.y, w1.z, w1.w};
      #pragma unroll
      for (int i = 0; i < 8; ++i)
        #pragma unroll
        for (int j = 0; j < 8; ++j)
          acc[i][j] = fmaf(av[i], wv[j], acc[i][j]);
    }
    __syncthreads();
  }

  const int n0 = b * T_N + t0;
  #pragma unroll
  for (int i = 0; i < 8; ++i) {
    const int t = tx * 8 + i;
    float4 o0, o1;
    o0.x = acc[i][0] + bj[0]; o0.y = acc[i][1] + bj[1];
    o0.z = acc[i][2] + bj[2]; o0.w = acc[i][3] + bj[3];
    o1.x = acc[i][4] + bj[4]; o1.y = acc[i][5] + bj[5];
    o1.z = acc[i][6] + bj[6]; o1.w = acc[i][7] + bj[7];
    float* zr = ze + (size_t)(n0 + t) * D_N + ty * 8;
    *(float4*)zr       = o0;
    *(float4*)(zr + 4) = o1;
  }
}

// ---------------- distance GEMM + fused argmin
// grid N/128, block 256.  128 rows/block, loops all 1024 codes in 128-tiles.
// thread: tx -> 8 codes, ty -> 8 rows; argmin uses dist' = |e|^2 - 2 f.e
__global__ __launch_bounds__(256) void k_argmin(const float* __restrict__ ze,
                                                const float* __restrict__ E,
                                                const float* __restrict__ en,
                                                int* __restrict__ ind,
                                                float* __restrict__ ind_f) {
  __shared__ __align__(16) float fs[32][132];  // [d][row]
  __shared__ __align__(16) float es[32][132];  // [d][code]
  __shared__ float ens[K_N];

  const int n0  = blockIdx.x * 128;
  const int tid = threadIdx.x;
  const int tx  = tid & 15;   // code sub-tile
  const int ty  = tid >> 4;   // row sub-tile

  for (int f = tid; f < K_N; f += 256) ens[f] = en[f];

  float bestd[8];
  int   bestk[8];
  #pragma unroll
  for (int i = 0; i < 8; ++i) { bestd[i] = 3.4e38f; bestk[i] = 0; }

  for (int kt = 0; kt < K_N; kt += 128) {
    float acc[8][8];
    #pragma unroll
    for (int i = 0; i < 8; ++i)
      #pragma unroll
      for (int j = 0; j < 8; ++j) acc[i][j] = 0.f;

    for (int d0 = 0; d0 < D_N; d0 += 32) {
      __syncthreads();  // protect LDS from previous chunk's readers
      #pragma unroll
      for (int f = tid; f < 4096; f += 256) {
        const int r = f >> 5, dd = f & 31;
        fs[dd][r] = ze[(size_t)(n0 + r) * D_N + d0 + dd];
      }
      #pragma unroll
      for (int f = tid; f < 4096; f += 256) {
        const int kk = f >> 5, dd = f & 31;
        es[dd][kk] = E[(size_t)(kt + kk) * D_N + d0 + dd];
      }
      __syncthreads();
      #pragma unroll
      for (int d = 0; d < 32; ++d) {
        const float4 e0 = *(const float4*)&es[d][tx * 8];
        const float4 e1 = *(const float4*)&es[d][tx * 8 + 4];
        const float4 a0 = *(const float4*)&fs[d][ty * 8];
        const float4 a1 = *(const float4*)&fs[d][ty * 8 + 4];
        const float av[8] = {a0.x, a0.y, a0.z, a0.w, a1.x, a1.y, a1.z, a1.w};
        const float ev[8] = {e0.x, e0.y, e0.z, e0.w, e1.x, e1.y, e1.z, e1.w};
        #pragma unroll
        for (int i = 0; i < 8; ++i)
          #pragma unroll
          for (int j = 0; j < 8; ++j)
            acc[i][j] = fmaf(av[i], ev[j], acc[i][j]);
      }
    }
    // fold this 128-code tile into running best (k ascending -> '<' keeps first)
    #pragma unroll
    for (int j = 0; j < 8; ++j) {
      const int k = kt + tx * 8 + j;
      const float enk = ens[k];
      #pragma unroll
      for (int i = 0; i < 8; ++i) {
        const float dv = enk - 2.0f * acc[i][j];
        if (dv < bestd[i]) { bestd[i] = dv; bestk[i] = k; }
      }
    }
  }

  // reduce across the 16 tx lanes (contiguous 16-lane groups in a wave)
  #pragma unroll
  for (int i = 0; i < 8; ++i) {
    #pragma unroll
    for (int off = 1; off < 16; off <<= 1) {
      const float od = __shfl_xor(bestd[i], off);
      const int   ok = __shfl_xor(bestk[i], off);
      if (od < bestd[i] || (od == bestd[i] && ok < bestk[i])) {
        bestd[i] = od; bestk[i] = ok;
      }
    }
    if (tx == 0) {
      const int n = n0 + ty * 8 + i;
      ind[n]   = bestk[i];
      ind_f[n] = (float)bestk[i];
    }
  }
}

// ---------------- gather codes, write out[B,D,T] transposed, diff partials
// grid (T/64, B), block 256.
__global__ __launch_bounds__(256) void k_out(const float* __restrict__ ze,
                                             const float* __restrict__ E,
                                             const int* __restrict__ ind,
                                             float* __restrict__ out,
                                             float* __restrict__ part) {
  __shared__ float es[64][129];   // [t][d], pad 129 -> conflict-free transpose
  __shared__ int   si[64];
  __shared__ float wsum[4];

  const int b   = blockIdx.y;
  const int t0  = blockIdx.x * 64;
  const int tid = threadIdx.x;

  if (tid < 64) si[tid] = ind[b * T_N + t0 + tid];
  __syncthreads();

  float psum = 0.f;
  const float* zeb = ze + ((size_t)b * T_N + t0) * D_N;
  #pragma unroll
  for (int f = tid; f < 8192; f += 256) {
    const int t = f >> 7, d = f & 127;
    const float ev = E[(size_t)si[t] * D_N + d];
    const float zv = zeb[(size_t)t * D_N + d];
    const float df = ev - zv;
    psum += df * df;
    es[t][d] = ev;
  }
  __syncthreads();

  float* ob = out + (size_t)b * D_N * T_N + t0;
  #pragma unroll
  for (int g = tid; g < 8192; g += 256) {
    const int d = g >> 6, t = g & 63;
    ob[(size_t)d * T_N + t] = es[t][d];
  }

  #pragma unroll
  for (int off = 32; off > 0; off >>= 1) psum += __shfl_down(psum, off);
  if ((tid & 63) == 0) wsum[tid >> 6] = psum;
  __syncthreads();
  if (tid == 0)
    part[blockIdx.y * gridDim.x + blockIdx.x] = wsum[0] + wsum[1] + wsum[2] + wsum[3];
}

// ---------------- final deterministic diff reduction ----------------
__global__ __launch_bounds__(256) void k_diff(const float* __restrict__ part,
                                              float* __restrict__ diff_out) {
  __shared__ double wsd[4];
  const int tid = threadIdx.x;
  double s = 0.0;
  for (int i = tid; i < 2048; i += 256) s += (double)part[i];
  #pragma unroll
  for (int off = 32; off > 0; off >>= 1) s += __shfl_down(s, off);
  if ((tid & 63) == 0) wsd[tid >> 6] = s;
  __syncthreads();
  if (tid == 0) {
    const double tot = wsd[0] + wsd[1] + wsd[2] + wsd[3];
    // diff = 10 * (0.25 + 1.0) * mean((z_q - z_e)^2)
    diff_out[0] = (float)(12.5 * tot / (double)((size_t)N_N * D_N));
  }
}

extern "C" void kernel_launch(void* const* d_in, const int* in_sizes, int n_in,
                              void* d_out, int out_size, void* d_ws, size_t ws_size,
                              hipStream_t stream) {
  const float* z    = (const float*)d_in[0];  // [B, C, T]
  const float* W    = (const float*)d_in[1];  // [D, C]
  const float* bias = (const float*)d_in[2];  // [D]
  const float* E    = (const float*)d_in[3];  // [K, D]

  float* out = (float*)d_out;
  float* out_q    = out;                 // [B, D, T]
  float* out_diff = out + 16777216;      // scalar
  float* out_ind  = out + 16777217;      // [B, T] as float

  char* ws = (char*)d_ws;
  float* ze   = (float*)(ws + ZE_OFF);
  float* en   = (float*)(ws + EN_OFF);
  int*   ind  = (int*)(ws + IND_OFF);
  float* part = (float*)(ws + PART_OFF);

  k_enorm<<<K_N, 64, 0, stream>>>(E, en);
  k_proj<<<dim3(T_N / 128, B_N), 256, 0, stream>>>(z, W, bias, ze);
  k_argmin<<<N_N / 128, 256, 0, stream>>>(ze, E, en, ind, out_ind);
  k_out<<<dim3(T_N / 64, B_N), 256, 0, stream>>>(ze, E, ind, out_q, part);
  k_diff<<<1, 256, 0, stream>>>(part, out_diff);
}

// Round 2
// 662.176 us; speedup vs baseline: 2.2100x; 2.2100x over previous
//
#include <hip/hip_runtime.h>

#define B_N 32
#define C_N 512
#define T_N 4096
#define D_N 128
#define K_N 1024
#define N_N (B_N * T_N)   // 131072

typedef _Float16 f16x8 __attribute__((ext_vector_type(8)));
typedef float    f32x4 __attribute__((ext_vector_type(4)));

// ---------------- workspace layout (bytes) ----------------
// ze_swz : [N/16][8 chunks][64 lanes][8 halves]      = 67,108,864
// E_swz  : [8 kt][12 c][8 mi][64 lanes][8 halves]    =    786,432
// en_s   : [K] float (scaled by 4096)                =      4,096
// ind    : [N] int                                   =    524,288
// part   : [2048] float                              =      8,192
#define ZSWZ_OFF 0
#define ESWZ_OFF 67108864
#define ENS_OFF  67895296
#define IND_OFF  67899392
#define PART_OFF 68423680

#define GLL(g, s) __builtin_amdgcn_global_load_lds( \
    (const __attribute__((address_space(1))) unsigned int*)(g), \
    (__attribute__((address_space(3))) unsigned int*)(s), 16, 0, 0)

// ---------------- codebook prep: norms (x4096) + swizzled fp16-split E
// E_swz element16 index: (kt*12 + c)*512 + mi*64 + lk*16 + lrow
//   code = kt*128 + mi*16 + lrow ; k = c*32 + lk*8 + i
//   c in 0..3: eh[k] ; 4..7: el[k-128] ; 8..11: eh[k-256]
__global__ __launch_bounds__(128) void k_eprep(const float* __restrict__ E,
                                               _Float16* __restrict__ eswz,
                                               float* __restrict__ ens) {
  __shared__ float s2[2];
  const int code = blockIdx.x, d = threadIdx.x;
  const float e  = E[(size_t)code * D_N + d];
  const float es = e * 64.f;
  const _Float16 eh = (_Float16)es;
  const _Float16 el = (_Float16)(es - (float)eh);

  float sq = es * es;
  #pragma unroll
  for (int off = 32; off > 0; off >>= 1) sq += __shfl_down(sq, off);
  if ((d & 63) == 0) s2[d >> 6] = sq;
  __syncthreads();
  if (d == 0) ens[code] = s2[0] + s2[1];   // = 4096 * sum(e^2)

  const int kt = code >> 7, mi = (code >> 4) & 7, lrow = code & 15;
  const int lk = (d >> 3) & 3, i = d & 7, cb = d >> 5;
  const size_t tile = (size_t)kt * 12;
  #define PUT(c, v) eswz[(((tile + (c)) * 512 + mi * 64 + lk * 16 + lrow) << 3) + i] = (v)
  PUT(cb, eh);
  PUT(4 + cb, el);
  PUT(8 + cb, eh);
  #undef PUT
}

// ---------------- projection GEMM: ze[n,d] = sum_c z[b,c,t]*W[d,c] + bias[d]
// fp32 vector math; epilogue writes fp16-split swizzled ze (x64 scale).
// ze_swz element16 index: (rg*8 + cu)*64 + lk*16 + (n&15)
//   rg = n>>4 ; cu 0..3: fh d=cu*32+lk*8+i ; cu 4..7: fl d=(cu-4)*32+lk*8+i
__global__ __launch_bounds__(256) void k_proj(const float* __restrict__ z,
                                              const float* __restrict__ W,
                                              const float* __restrict__ bias,
                                              f16x8* __restrict__ zswz) {
  __shared__ __align__(16) float zs[32][128];
  __shared__ __align__(16) float wsm[32][132];

  const int b   = blockIdx.y;
  const int t0  = blockIdx.x * 128;
  const int tid = threadIdx.x;
  const int tx  = tid & 15;   // t sub-tile (8 t each)
  const int ty  = tid >> 4;   // d sub-tile (8 d each)

  float acc[8][8];
  #pragma unroll
  for (int i = 0; i < 8; ++i)
    #pragma unroll
    for (int j = 0; j < 8; ++j) acc[i][j] = 0.f;

  float bj[8];
  #pragma unroll
  for (int j = 0; j < 8; ++j) bj[j] = bias[ty * 8 + j];

  const float* zb = z + (size_t)b * C_N * T_N + t0;

  for (int c0 = 0; c0 < C_N; c0 += 32) {
    #pragma unroll
    for (int u = tid; u < 1024; u += 256) {
      const int cc = u >> 5, t4 = u & 31;
      *(float4*)&zs[cc][t4 * 4] =
          *(const float4*)&zb[(size_t)(c0 + cc) * T_N + t4 * 4];
    }
    #pragma unroll
    for (int f = tid; f < 4096; f += 256) {
      const int d = f >> 5, cc = f & 31;
      wsm[cc][d] = W[d * C_N + c0 + cc];
    }
    __syncthreads();
    #pragma unroll
    for (int c = 0; c < 32; ++c) {
      const float4 a0 = *(const float4*)&zs[c][tx * 8];
      const float4 a1 = *(const float4*)&zs[c][tx * 8 + 4];
      const float4 w0 = *(const float4*)&wsm[c][ty * 8];
      const float4 w1 = *(const float4*)&wsm[c][ty * 8 + 4];
      const float av[8] = {a0.x, a0.y, a0.z, a0.w, a1.x, a1.y, a1.z, a1.w};
      const float wv[8] = {w0.x, w0.y, w0.z, w0.w, w1.x, w1.y, w1.z, w1.w};
      #pragma unroll
      for (int i = 0; i < 8; ++i)
        #pragma unroll
        for (int j = 0; j < 8; ++j)
          acc[i][j] = fmaf(av[i], wv[j], acc[i][j]);
    }
    __syncthreads();
  }

  const int n0 = b * T_N + t0;
  const int cu = ty >> 2, lk = ty & 3;
  #pragma unroll
  for (int i = 0; i < 8; ++i) {
    const int n = n0 + tx * 8 + i;
    f16x8 vh, vl;
    #pragma unroll
    for (int j = 0; j < 8; ++j) {
      const float x = (acc[i][j] + bj[j]) * 64.f;
      const _Float16 h = (_Float16)x;
      vh[j] = h;
      vl[j] = (_Float16)(x - (float)h);
    }
    const size_t idx = ((size_t)(n >> 4) * 8 + cu) * 64 + lk * 16 + (n & 15);
    zswz[idx]       = vh;
    zswz[idx + 256] = vl;   // cu+4 block
  }
}

// ---------------- distance GEMM (fp16x3 MFMA) + fused argmin
// block: 128 rows x (loop 8 kt of 128 codes), 4 waves (wr,wc) each 64x64.
// D[m=code][n=row]; A = E_swz chunks (LDS dbuf), B = ze_swz rows (LDS, resident).
__global__ __launch_bounds__(256) void k_argmin(const f16x8* __restrict__ zswz,
                                                const f16x8* __restrict__ eswz,
                                                const float* __restrict__ ens,
                                                int* __restrict__ ind,
                                                float* __restrict__ indf) {
  __shared__ f16x8 rows[4096];     // 64 KB, linear = global layout
  __shared__ f16x8 abuf[2][512];   // 2 x 8 KB chunk double-buffer

  const int tid = threadIdx.x;
  const int l   = tid & 63, w = tid >> 6;
  const int wr  = w >> 1, wc = w & 1;
  const int blk = blockIdx.x;

  // stage this block's 128 rows (64 KB contiguous)
  const char* zsrc = (const char*)zswz + (size_t)blk * 65536;
  #pragma unroll
  for (int s = 0; s < 16; ++s)
    GLL(zsrc + s * 4096 + tid * 16, &rows[s * 256 + w * 64]);

  // stage first A chunk
  {
    const char* asrc = (const char*)eswz;
    GLL(asrc + tid * 16,        &abuf[0][w * 64]);
    GLL(asrc + 4096 + tid * 16, &abuf[0][256 + w * 64]);
  }
  __syncthreads();

  float bestd[4];
  int   bestk[4];
  #pragma unroll
  for (int nf = 0; nf < 4; ++nf) { bestd[nf] = 3.4e38f; bestk[nf] = 0; }

  int buf = 0;
  for (int kt = 0; kt < 8; ++kt) {
    f32x4 acc[4][4];
    #pragma unroll
    for (int mi = 0; mi < 4; ++mi)
      #pragma unroll
      for (int nf = 0; nf < 4; ++nf) acc[mi][nf] = (f32x4)0.f;

    for (int c = 0; c < 12; ++c) {
      // prefetch next chunk
      int nkt = kt, nc = c + 1;
      if (nc == 12) { nc = 0; ++nkt; }
      if (nkt < 8) {
        const char* asrc = (const char*)eswz + ((size_t)(nkt * 12 + nc) * 512) * 16;
        GLL(asrc + tid * 16,        &abuf[buf ^ 1][w * 64]);
        GLL(asrc + 4096 + tid * 16, &abuf[buf ^ 1][256 + w * 64]);
      }
      const int cu = (c < 8) ? (c & 3) : (c - 4);
      f16x8 bfr[4], afr[4];
      #pragma unroll
      for (int nf = 0; nf < 4; ++nf)
        bfr[nf] = rows[((wc * 4 + nf) * 8 + cu) * 64 + l];
      #pragma unroll
      for (int mi = 0; mi < 4; ++mi)
        afr[mi] = abuf[buf][(wr * 4 + mi) * 64 + l];
      #pragma unroll
      for (int mi = 0; mi < 4; ++mi)
        #pragma unroll
        for (int nf = 0; nf < 4; ++nf)
          acc[mi][nf] = __builtin_amdgcn_mfma_f32_16x16x32_f16(
              afr[mi], bfr[nf], acc[mi][nf], 0, 0, 0);
      __syncthreads();
      buf ^= 1;
    }

    // fold this 128-code tile into running per-lane best
    #pragma unroll
    for (int mi = 0; mi < 4; ++mi) {
      const int cbase = kt * 128 + wr * 64 + mi * 16 + ((l >> 4) << 2);
      const float4 e4 = *(const float4*)&ens[cbase];
      const float ev[4] = {e4.x, e4.y, e4.z, e4.w};
      #pragma unroll
      for (int r = 0; r < 4; ++r) {
        const int k = cbase + r;
        #pragma unroll
        for (int nf = 0; nf < 4; ++nf) {
          const float dv = ev[r] - 2.0f * acc[mi][nf][r];
          if (dv < bestd[nf]) { bestd[nf] = dv; bestk[nf] = k; }
        }
      }
    }
  }

  // reduce over the 4 lane-groups sharing a row (xor 16, 32)
  float* sd = (float*)&rows[0];
  int*   sk = (int*)((float*)&rows[0] + 256);
  #pragma unroll
  for (int nf = 0; nf < 4; ++nf) {
    float d = bestd[nf]; int k = bestk[nf];
    #pragma unroll
    for (int off = 16; off < 64; off <<= 1) {
      const float od = __shfl_xor(d, off);
      const int   ok = __shfl_xor(k, off);
      if (od < d || (od == d && ok < k)) { d = od; k = ok; }
    }
    if (l < 16) {
      sd[wr * 128 + wc * 64 + nf * 16 + l] = d;
      sk[wr * 128 + wc * 64 + nf * 16 + l] = k;
    }
  }
  __syncthreads();
  if (tid < 128) {
    float d0 = sd[tid], d1 = sd[128 + tid];
    int   k0 = sk[tid], k1 = sk[128 + tid];
    if (d1 < d0 || (d1 == d0 && k1 < k0)) { d0 = d1; k0 = k1; }
    const int n = blk * 128 + tid;
    ind[n]  = k0;
    indf[n] = (float)k0;
  }
}

// ---------------- gather codes, write out[B,D,T] transposed, diff partials
__global__ __launch_bounds__(256) void k_out(const f16x8* __restrict__ zswz,
                                             const float* __restrict__ E,
                                             const int* __restrict__ ind,
                                             float* __restrict__ out,
                                             float* __restrict__ part) {
  __shared__ float es[64][129];
  __shared__ int   si[64];
  __shared__ float wsum[4];

  const int b   = blockIdx.y;
  const int t0  = blockIdx.x * 64;
  const int tid = threadIdx.x;

  if (tid < 64) si[tid] = ind[b * T_N + t0 + tid];
  __syncthreads();

  float psum = 0.f;
  const int n0 = b * T_N + t0;
  #pragma unroll
  for (int u = tid; u < 1024; u += 256) {
    const int t = u >> 4, db = u & 15;
    const int n = n0 + t;
    const size_t base = ((size_t)(n >> 4) * 8 + (db >> 2)) * 64 + (db & 3) * 16 + (n & 15);
    const f16x8 vh = zswz[base];
    const f16x8 vl = zswz[base + 256];
    const float* ep = &E[(size_t)si[t] * D_N + db * 8];
    const float4 e0 = *(const float4*)ep;
    const float4 e1 = *(const float4*)(ep + 4);
    const float evv[8] = {e0.x, e0.y, e0.z, e0.w, e1.x, e1.y, e1.z, e1.w};
    #pragma unroll
    for (int j = 0; j < 8; ++j) {
      const float zv = ((float)vh[j] + (float)vl[j]) * 0.015625f;
      const float df = evv[j] - zv;
      psum += df * df;
      es[t][db * 8 + j] = evv[j];
    }
  }
  __syncthreads();

  float* ob = out + (size_t)b * D_N * T_N + t0;
  #pragma unroll
  for (int g = tid; g < 8192; g += 256) {
    const int d = g >> 6, t = g & 63;
    ob[(size_t)d * T_N + t] = es[t][d];
  }

  #pragma unroll
  for (int off = 32; off > 0; off >>= 1) psum += __shfl_down(psum, off);
  if ((tid & 63) == 0) wsum[tid >> 6] = psum;
  __syncthreads();
  if (tid == 0)
    part[blockIdx.y * gridDim.x + blockIdx.x] = wsum[0] + wsum[1] + wsum[2] + wsum[3];
}

// ---------------- final deterministic diff reduction ----------------
__global__ __launch_bounds__(256) void k_diff(const float* __restrict__ part,
                                              float* __restrict__ diff_out) {
  __shared__ double wsd[4];
  const int tid = threadIdx.x;
  double s = 0.0;
  for (int i = tid; i < 2048; i += 256) s += (double)part[i];
  #pragma unroll
  for (int off = 32; off > 0; off >>= 1) s += __shfl_down(s, off);
  if ((tid & 63) == 0) wsd[tid >> 6] = s;
  __syncthreads();
  if (tid == 0) {
    const double tot = wsd[0] + wsd[1] + wsd[2] + wsd[3];
    diff_out[0] = (float)(12.5 * tot / (double)((size_t)N_N * D_N));
  }
}

extern "C" void kernel_launch(void* const* d_in, const int* in_sizes, int n_in,
                              void* d_out, int out_size, void* d_ws, size_t ws_size,
                              hipStream_t stream) {
  const float* z    = (const float*)d_in[0];  // [B, C, T]
  const float* W    = (const float*)d_in[1];  // [D, C]
  const float* bias = (const float*)d_in[2];  // [D]
  const float* E    = (const float*)d_in[3];  // [K, D]

  float* out = (float*)d_out;
  float* out_q    = out;                 // [B, D, T]
  float* out_diff = out + 16777216;      // scalar
  float* out_ind  = out + 16777217;      // [B, T] as float

  char* ws = (char*)d_ws;
  f16x8*    zswz = (f16x8*)(ws + ZSWZ_OFF);
  _Float16* eswz = (_Float16*)(ws + ESWZ_OFF);
  float*    ens  = (float*)(ws + ENS_OFF);
  int*      ind  = (int*)(ws + IND_OFF);
  float*    part = (float*)(ws + PART_OFF);

  k_eprep<<<K_N, 128, 0, stream>>>(E, eswz, ens);
  k_proj<<<dim3(T_N / 128, B_N), 256, 0, stream>>>(z, W, bias, zswz);
  k_argmin<<<N_N / 128, 256, 0, stream>>>(zswz, (const f16x8*)eswz, ens, ind, out_ind);
  k_out<<<dim3(T_N / 64, B_N), 256, 0, stream>>>(zswz, E, ind, out_q, part);
  k_diff<<<1, 256, 0, stream>>>(part, out_diff);
}

// Round 3
// 243.266 us; speedup vs baseline: 6.0158x; 2.7220x over previous
//
#include <hip/hip_runtime.h>

#define B_N 32
#define C_N 512
#define T_N 4096
#define D_N 128
#define K_N 1024
#define N_N (B_N * T_N)   // 131072

typedef _Float16 f16x8 __attribute__((ext_vector_type(8)));
typedef float    f32x4 __attribute__((ext_vector_type(4)));

// ---------------- workspace layout (bytes) ----------------
// ze_swz : [N/16][8 chunks][64 lanes][8 halves]      = 67,108,864
// E_swz  : [8 kt][12 c][8 mi][64 lanes][8 halves]    =    786,432
// en_s   : [K] float (scaled by 4096)                =      4,096
// ind    : [N] int                                   =    524,288
// part   : [2048] float                              =      8,192
// w_swz  : [16 kc][2 hi/lo][4096 halves]             =    262,144
#define ZSWZ_OFF 0
#define ESWZ_OFF 67108864
#define ENS_OFF  67895296
#define IND_OFF  67899392
#define PART_OFF 68423680
#define WSWZ_OFF 68431872

#define GLL(g, s) __builtin_amdgcn_global_load_lds( \
    (const __attribute__((address_space(1))) unsigned int*)(g), \
    (__attribute__((address_space(3))) unsigned int*)(s), 16, 0, 0)

// ---------------- codebook prep: norms (x4096) + swizzled fp16-split E
__global__ __launch_bounds__(128) void k_eprep(const float* __restrict__ E,
                                               _Float16* __restrict__ eswz,
                                               float* __restrict__ ens) {
  __shared__ float s2[2];
  const int code = blockIdx.x, d = threadIdx.x;
  const float e  = E[(size_t)code * D_N + d];
  const float es = e * 64.f;
  const _Float16 eh = (_Float16)es;
  const _Float16 el = (_Float16)(es - (float)eh);

  float sq = es * es;
  #pragma unroll
  for (int off = 32; off > 0; off >>= 1) sq += __shfl_down(sq, off);
  if ((d & 63) == 0) s2[d >> 6] = sq;
  __syncthreads();
  if (d == 0) ens[code] = s2[0] + s2[1];   // = 4096 * sum(e^2)

  const int kt = code >> 7, mi = (code >> 4) & 7, lrow = code & 15;
  const int lk = (d >> 3) & 3, i = d & 7, cb = d >> 5;
  const size_t tile = (size_t)kt * 12;
  #define PUT(c, v) eswz[(((tile + (c)) * 512 + mi * 64 + lk * 16 + lrow) << 3) + i] = (v)
  PUT(cb, eh);
  PUT(4 + cb, el);
  PUT(8 + cb, eh);
  #undef PUT
}

// ---------------- W prep: frag-layout fp16 split of proj_w (x8 scale)
// wswz halves: kc*8192 + (nf*64 + lane)*8 + j ; hi at +0, lo at +4096
//   d = nf*16 + (lane&15) ; c = kc*32 + (lane>>4)*8 + j
__global__ __launch_bounds__(256) void k_wprep(const float* __restrict__ W,
                                               _Float16* __restrict__ wswz) {
  const int e = blockIdx.x * 256 + threadIdx.x;   // 65536 elements
  const int d = e >> 9, c = e & 511;
  const float x = W[d * C_N + c] * 8.f;
  const _Float16 h  = (_Float16)x;
  const _Float16 lo = (_Float16)(x - (float)h);
  const int kc = c >> 5, gg = (c >> 3) & 3, j = c & 7;
  const int nf = d >> 4, ll = gg * 16 + (d & 15);
  const size_t base = (size_t)kc * 8192 + ((size_t)nf * 64 + ll) * 8 + j;
  wswz[base]        = h;
  wswz[base + 4096] = lo;
}

// ---------------- projection GEMM via fp16x3 MFMA
// block: 128 t x 128 d, K = C = 512 in 16 chunks of 32.
// A = z (hi/lo built in-register from fp32 LDS tile), B = wswz frags.
// Output written as fp16-split swizzled ze (x64 scale overall).
__global__ __launch_bounds__(256, 2) void k_projm(const float* __restrict__ z,
                                                  const _Float16* __restrict__ wswz,
                                                  const float* __restrict__ bias,
                                                  f16x8* __restrict__ zswz) {
  __shared__ __align__(16) char lds[65536];  // zbuf[2]@0 (16KB ea), wbuf[2]@32KB

  const int tid = threadIdx.x;
  const int l   = tid & 63, w = tid >> 6;
  const int g   = l >> 4, li = l & 15;
  const int b   = blockIdx.y, t0 = blockIdx.x * 128;
  const float* zb = z + (size_t)b * C_N * T_N + t0;

  float bs[8];
  #pragma unroll
  for (int nf = 0; nf < 8; ++nf) bs[nf] = bias[nf * 16 + li] * 64.f;

  f32x4 acc[2][8];
  #pragma unroll
  for (int mi = 0; mi < 2; ++mi)
    #pragma unroll
    for (int nf = 0; nf < 8; ++nf) acc[mi][nf] = (f32x4)0.f;

  auto stage = [&](int kc, int buf) {
    char* zdst = lds + buf * 16384;
    char* wdst = lds + 32768 + buf * 16384;
    #pragma unroll
    for (int s = 0; s < 4; ++s) {
      const int q = w * 4 + s;                    // wave-uniform
      const unsigned v = q * 64 + l;              // dest float4 slot
      const unsigned u = v ^ (((v >> 8) & 1) << 2);  // bit4^bit10 dword swizzle
      GLL((const char*)zb +
              ((size_t)(kc * 32 + (u >> 5)) * T_N + (size_t)(u & 31) * 4) * 4,
          zdst + q * 1024);
      GLL((const char*)wswz + (size_t)kc * 16384 + q * 1024 + l * 16,
          wdst + q * 1024);
    }
  };

  stage(0, 0);
  __syncthreads();

  int buf = 0;
  for (int kc = 0; kc < 16; ++kc) {
    if (kc + 1 < 16) stage(kc + 1, buf ^ 1);

    const float* zl = (const float*)(lds + buf * 16384);
    const f16x8* wb = (const f16x8*)(lds + 32768 + buf * 16384);

    f16x8 ah[2], al[2];
    #pragma unroll
    for (int mi = 0; mi < 2; ++mi) {
      const int mt = w * 2 + mi;
      const int a0 = (g * 1024 + mt * 16 + li) ^ ((g & 1) << 4);
      #pragma unroll
      for (int j = 0; j < 8; ++j) {
        const float x = zl[a0 + j * 128] * 8.f;
        const _Float16 h = (_Float16)x;
        ah[mi][j] = h;
        al[mi][j] = (_Float16)(x - (float)h);
      }
    }
    f16x8 bh[8], bl[8];
    #pragma unroll
    for (int nf = 0; nf < 8; ++nf) {
      bh[nf] = wb[nf * 64 + l];
      bl[nf] = wb[512 + nf * 64 + l];
    }
    #pragma unroll
    for (int mi = 0; mi < 2; ++mi)
      #pragma unroll
      for (int nf = 0; nf < 8; ++nf) {
        acc[mi][nf] = __builtin_amdgcn_mfma_f32_16x16x32_f16(ah[mi], bh[nf], acc[mi][nf], 0, 0, 0);
        acc[mi][nf] = __builtin_amdgcn_mfma_f32_16x16x32_f16(al[mi], bh[nf], acc[mi][nf], 0, 0, 0);
        acc[mi][nf] = __builtin_amdgcn_mfma_f32_16x16x32_f16(ah[mi], bl[nf], acc[mi][nf], 0, 0, 0);
      }
    __syncthreads();
    buf ^= 1;
  }

  // epilogue: two-phase LDS transpose -> fp16-split swizzled global stores
  unsigned* cs = (unsigned*)lds;   // [128][68] uint (hi|lo<<16), 16B-aligned rows
  const int n0 = b * T_N + t0;
  for (int p = 0; p < 2; ++p) {
    #pragma unroll
    for (int mi = 0; mi < 2; ++mi) {
      const int trow = (w * 2 + mi) * 16 + g * 4;
      #pragma unroll
      for (int nfl = 0; nfl < 4; ++nfl) {
        const int nf = p * 4 + nfl;
        #pragma unroll
        for (int r = 0; r < 4; ++r) {
          const float x = acc[mi][nf][r] + bs[nf];
          const _Float16 h  = (_Float16)x;
          const _Float16 lo = (_Float16)(x - (float)h);
          cs[(trow + r) * 68 + nfl * 16 + li] =
              (unsigned)__builtin_bit_cast(unsigned short, h) |
              ((unsigned)__builtin_bit_cast(unsigned short, lo) << 16);
        }
      }
    }
    __syncthreads();
    #pragma unroll
    for (int i = 0; i < 4; ++i) {
      const int u = i * 256 + tid;
      const int t = u & 127, dc = u >> 7;
      f16x8 vh, vl;
      #pragma unroll
      for (int e = 0; e < 8; ++e) {
        const unsigned vv = cs[t * 68 + dc * 8 + e];
        vh[e] = __builtin_bit_cast(_Float16, (unsigned short)(vv & 0xffff));
        vl[e] = __builtin_bit_cast(_Float16, (unsigned short)(vv >> 16));
      }
      const int n = n0 + t;
      const int cu = p * 2 + (dc >> 2), lk = dc & 3;
      const size_t idx = ((size_t)(n >> 4) * 8 + cu) * 64 + lk * 16 + (n & 15);
      zswz[idx]       = vh;
      zswz[idx + 256] = vl;
    }
    __syncthreads();
  }
}

// ---------------- distance GEMM (fp16x3 MFMA) + fused argmin
__global__ __launch_bounds__(256) void k_argmin(const f16x8* __restrict__ zswz,
                                                const f16x8* __restrict__ eswz,
                                                const float* __restrict__ ens,
                                                int* __restrict__ ind,
                                                float* __restrict__ indf) {
  __shared__ f16x8 rows[4096];     // 64 KB, linear = global layout
  __shared__ f16x8 abuf[2][512];   // 2 x 8 KB chunk double-buffer

  const int tid = threadIdx.x;
  const int l   = tid & 63, w = tid >> 6;
  const int wr  = w >> 1, wc = w & 1;
  const int blk = blockIdx.x;

  const char* zsrc = (const char*)zswz + (size_t)blk * 65536;
  #pragma unroll
  for (int s = 0; s < 16; ++s)
    GLL(zsrc + s * 4096 + tid * 16, &rows[s * 256 + w * 64]);

  {
    const char* asrc = (const char*)eswz;
    GLL(asrc + tid * 16,        &abuf[0][w * 64]);
    GLL(asrc + 4096 + tid * 16, &abuf[0][256 + w * 64]);
  }
  __syncthreads();

  float bestd[4];
  int   bestk[4];
  #pragma unroll
  for (int nf = 0; nf < 4; ++nf) { bestd[nf] = 3.4e38f; bestk[nf] = 0; }

  int buf = 0;
  for (int kt = 0; kt < 8; ++kt) {
    f32x4 acc[4][4];
    #pragma unroll
    for (int mi = 0; mi < 4; ++mi)
      #pragma unroll
      for (int nf = 0; nf < 4; ++nf) acc[mi][nf] = (f32x4)0.f;

    for (int c = 0; c < 12; ++c) {
      int nkt = kt, nc = c + 1;
      if (nc == 12) { nc = 0; ++nkt; }
      if (nkt < 8) {
        const char* asrc = (const char*)eswz + ((size_t)(nkt * 12 + nc) * 512) * 16;
        GLL(asrc + tid * 16,        &abuf[buf ^ 1][w * 64]);
        GLL(asrc + 4096 + tid * 16, &abuf[buf ^ 1][256 + w * 64]);
      }
      const int cu = (c < 8) ? (c & 3) : (c - 4);
      f16x8 bfr[4], afr[4];
      #pragma unroll
      for (int nf = 0; nf < 4; ++nf)
        bfr[nf] = rows[((wc * 4 + nf) * 8 + cu) * 64 + l];
      #pragma unroll
      for (int mi = 0; mi < 4; ++mi)
        afr[mi] = abuf[buf][(wr * 4 + mi) * 64 + l];
      #pragma unroll
      for (int mi = 0; mi < 4; ++mi)
        #pragma unroll
        for (int nf = 0; nf < 4; ++nf)
          acc[mi][nf] = __builtin_amdgcn_mfma_f32_16x16x32_f16(
              afr[mi], bfr[nf], acc[mi][nf], 0, 0, 0);
      __syncthreads();
      buf ^= 1;
    }

    #pragma unroll
    for (int mi = 0; mi < 4; ++mi) {
      const int cbase = kt * 128 + wr * 64 + mi * 16 + ((l >> 4) << 2);
      const float4 e4 = *(const float4*)&ens[cbase];
      const float ev[4] = {e4.x, e4.y, e4.z, e4.w};
      #pragma unroll
      for (int r = 0; r < 4; ++r) {
        const int k = cbase + r;
        #pragma unroll
        for (int nf = 0; nf < 4; ++nf) {
          const float dv = ev[r] - 2.0f * acc[mi][nf][r];
          if (dv < bestd[nf]) { bestd[nf] = dv; bestk[nf] = k; }
        }
      }
    }
  }

  float* sd = (float*)&rows[0];
  int*   sk = (int*)((float*)&rows[0] + 256);
  #pragma unroll
  for (int nf = 0; nf < 4; ++nf) {
    float d = bestd[nf]; int k = bestk[nf];
    #pragma unroll
    for (int off = 16; off < 64; off <<= 1) {
      const float od = __shfl_xor(d, off);
      const int   ok = __shfl_xor(k, off);
      if (od < d || (od == d && ok < k)) { d = od; k = ok; }
    }
    if (l < 16) {
      sd[wr * 128 + wc * 64 + nf * 16 + l] = d;
      sk[wr * 128 + wc * 64 + nf * 16 + l] = k;
    }
  }
  __syncthreads();
  if (tid < 128) {
    float d0 = sd[tid], d1 = sd[128 + tid];
    int   k0 = sk[tid], k1 = sk[128 + tid];
    if (d1 < d0 || (d1 == d0 && k1 < k0)) { d0 = d1; k0 = k1; }
    const int n = blk * 128 + tid;
    ind[n]  = k0;
    indf[n] = (float)k0;
  }
}

// ---------------- gather codes, write out[B,D,T] transposed, diff partials
__global__ __launch_bounds__(256) void k_out(const f16x8* __restrict__ zswz,
                                             const float* __restrict__ E,
                                             const int* __restrict__ ind,
                                             float* __restrict__ out,
                                             float* __restrict__ part) {
  __shared__ float es[64][129];
  __shared__ int   si[64];
  __shared__ float wsum[4];

  const int b   = blockIdx.y;
  const int t0  = blockIdx.x * 64;
  const int tid = threadIdx.x;

  if (tid < 64) si[tid] = ind[b * T_N + t0 + tid];
  __syncthreads();

  float psum = 0.f;
  const int n0 = b * T_N + t0;
  #pragma unroll
  for (int u = tid; u < 1024; u += 256) {
    const int t = u >> 4, db = u & 15;
    const int n = n0 + t;
    const size_t base = ((size_t)(n >> 4) * 8 + (db >> 2)) * 64 + (db & 3) * 16 + (n & 15);
    const f16x8 vh = zswz[base];
    const f16x8 vl = zswz[base + 256];
    const float* ep = &E[(size_t)si[t] * D_N + db * 8];
    const float4 e0 = *(const float4*)ep;
    const float4 e1 = *(const float4*)(ep + 4);
    const float evv[8] = {e0.x, e0.y, e0.z, e0.w, e1.x, e1.y, e1.z, e1.w};
    #pragma unroll
    for (int j = 0; j < 8; ++j) {
      const float zv = ((float)vh[j] + (float)vl[j]) * 0.015625f;
      const float df = evv[j] - zv;
      psum += df * df;
      es[t][db * 8 + j] = evv[j];
    }
  }
  __syncthreads();

  float* ob = out + (size_t)b * D_N * T_N + t0;
  #pragma unroll
  for (int g = tid; g < 8192; g += 256) {
    const int d = g >> 6, t = g & 63;
    ob[(size_t)d * T_N + t] = es[t][d];
  }

  #pragma unroll
  for (int off = 32; off > 0; off >>= 1) psum += __shfl_down(psum, off);
  if ((tid & 63) == 0) wsum[tid >> 6] = psum;
  __syncthreads();
  if (tid == 0)
    part[blockIdx.y * gridDim.x + blockIdx.x] = wsum[0] + wsum[1] + wsum[2] + wsum[3];
}

// ---------------- final deterministic diff reduction ----------------
__global__ __launch_bounds__(256) void k_diff(const float* __restrict__ part,
                                              float* __restrict__ diff_out) {
  __shared__ double wsd[4];
  const int tid = threadIdx.x;
  double s = 0.0;
  for (int i = tid; i < 2048; i += 256) s += (double)part[i];
  #pragma unroll
  for (int off = 32; off > 0; off >>= 1) s += __shfl_down(s, off);
  if ((tid & 63) == 0) wsd[tid >> 6] = s;
  __syncthreads();
  if (tid == 0) {
    const double tot = wsd[0] + wsd[1] + wsd[2] + wsd[3];
    diff_out[0] = (float)(12.5 * tot / (double)((size_t)N_N * D_N));
  }
}

extern "C" void kernel_launch(void* const* d_in, const int* in_sizes, int n_in,
                              void* d_out, int out_size, void* d_ws, size_t ws_size,
                              hipStream_t stream) {
  const float* z    = (const float*)d_in[0];  // [B, C, T]
  const float* W    = (const float*)d_in[1];  // [D, C]
  const float* bias = (const float*)d_in[2];  // [D]
  const float* E    = (const float*)d_in[3];  // [K, D]

  float* out = (float*)d_out;
  float* out_q    = out;                 // [B, D, T]
  float* out_diff = out + 16777216;      // scalar
  float* out_ind  = out + 16777217;      // [B, T] as float

  char* ws = (char*)d_ws;
  f16x8*    zswz = (f16x8*)(ws + ZSWZ_OFF);
  _Float16* eswz = (_Float16*)(ws + ESWZ_OFF);
  float*    ens  = (float*)(ws + ENS_OFF);
  int*      ind  = (int*)(ws + IND_OFF);
  float*    part = (float*)(ws + PART_OFF);
  _Float16* wswz = (_Float16*)(ws + WSWZ_OFF);

  k_eprep<<<K_N, 128, 0, stream>>>(E, eswz, ens);
  k_wprep<<<256, 256, 0, stream>>>(W, wswz);
  k_projm<<<dim3(T_N / 128, B_N), 256, 0, stream>>>(z, wswz, bias, zswz);
  k_argmin<<<N_N / 128, 256, 0, stream>>>(zswz, (const f16x8*)eswz, ens, ind, out_ind);
  k_out<<<dim3(T_N / 64, B_N), 256, 0, stream>>>(zswz, E, ind, out_q, part);
  k_diff<<<1, 256, 0, stream>>>(part, out_diff);
}